// Round 2
// baseline (1258.971 us; speedup 1.0000x reference)
//
#include <hip/hip_runtime.h>

// 2-layer GCN: x[N,512] @ W1[512,16] -> aggregate -> relu -> @ W2[16,40]
// -> aggregate -> +b2 -> log_softmax.  N=100000, E=3200000.
//
// Algebra: per layer, out[d] = dinv[d] * ( sum_{edges s->d} hs[s] + hs[d] ) + b
// where hs[v] = (x@W)[v] * dinv[v], dinv[v] = rsqrt(1 + in_deg[v]).
// So edge work is a pure gather + atomic add of pre-scaled features.

#define NFEAT_IN 512
#define NF1 16
#define NF2 40

// ---------------- degree ----------------
__global__ void k_count(const int* __restrict__ dst, int* __restrict__ deg, int E) {
  int e = blockIdx.x * 256 + threadIdx.x;
  if (e < E) atomicAdd(&deg[dst[e]], 1);
}

__global__ void k_dinv(const int* __restrict__ deg, float* __restrict__ dinv, int n) {
  int v = blockIdx.x * 256 + threadIdx.x;
  if (v < n) dinv[v] = rsqrtf((float)(deg[v] + 1));  // +1 self-loop
}

// ---------------- layer-1 gemm: h1s[v][f] = dinv[v] * sum_k x[v][k]*W1[k][f] ----------------
// 16 threads per node (one per f).  W1 transposed into LDS with +4 pad so the
// 16 distinct rows map to 8 bank-quads (2-way conflict == free).
__global__ void k_gemm1(const float* __restrict__ x, const float* __restrict__ W1,
                        const float* __restrict__ dinv, float* __restrict__ h1s, int n) {
  __shared__ float Wt[NF1][NFEAT_IN + 4];
  for (int i = threadIdx.x; i < NFEAT_IN * NF1; i += 256) {
    int k = i >> 4, f = i & 15;
    Wt[f][k] = W1[i];  // W1 is [512][16] row-major
  }
  __syncthreads();
  int tid = blockIdx.x * 256 + threadIdx.x;
  int v = tid >> 4, f = tid & 15;
  if (v >= n) return;
  const float4* xr = (const float4*)(x + (size_t)v * NFEAT_IN);
  const float4* wr = (const float4*)(&Wt[f][0]);  // row base 2064B -> 16B aligned
  float acc = 0.f;
#pragma unroll 8
  for (int k4 = 0; k4 < NFEAT_IN / 4; ++k4) {
    float4 a = xr[k4], w = wr[k4];
    acc = fmaf(a.x, w.x, acc);
    acc = fmaf(a.y, w.y, acc);
    acc = fmaf(a.z, w.z, acc);
    acc = fmaf(a.w, w.w, acc);
  }
  h1s[tid] = acc * dinv[v];
}

// ---------------- layer-1 scatter: agg1[d] += h1s[s], 16 lanes per edge ----------------
__global__ void k_scatter1(const int* __restrict__ src, const int* __restrict__ dst,
                           const float* __restrict__ h1s, float* __restrict__ agg1, int E) {
  int t = blockIdx.x * 256 + threadIdx.x;
  int e = t >> 4, f = t & 15;
  if (e < E) {
    int s = src[e], d = dst[e];
    atomicAdd(&agg1[d * NF1 + f], h1s[s * NF1 + f]);
  }
}

// ---------------- finalize1 + relu + gemm2 (fused), one thread per node ----------------
// a[f]   = relu(dinv[v]*(agg1[v][f] + h1s[v][f]) + b1[f])
// h2s[g] = dinv[v] * sum_f a[f]*W2[f][g]
__global__ void k_fin1g2(const float* __restrict__ agg1, const float* __restrict__ h1s,
                         const float* __restrict__ dinv, const float* __restrict__ b1,
                         const float* __restrict__ W2, float* __restrict__ h2s, int n) {
  __shared__ float W2s[NF1 * NF2];
  __shared__ float b1s[NF1];
  for (int i = threadIdx.x; i < NF1 * NF2; i += 256) W2s[i] = W2[i];
  if (threadIdx.x < NF1) b1s[threadIdx.x] = b1[threadIdx.x];
  __syncthreads();
  int v = blockIdx.x * 256 + threadIdx.x;
  if (v >= n) return;
  float dv = dinv[v];
  const float4* ar = (const float4*)(agg1 + (size_t)v * NF1);
  const float4* hr = (const float4*)(h1s + (size_t)v * NF1);
  float a[NF1];
#pragma unroll
  for (int i = 0; i < NF1 / 4; ++i) {
    float4 av = ar[i], hv = hr[i];
    float t0 = dv * (av.x + hv.x) + b1s[4 * i + 0];
    float t1 = dv * (av.y + hv.y) + b1s[4 * i + 1];
    float t2 = dv * (av.z + hv.z) + b1s[4 * i + 2];
    float t3 = dv * (av.w + hv.w) + b1s[4 * i + 3];
    a[4 * i + 0] = t0 > 0.f ? t0 : 0.f;
    a[4 * i + 1] = t1 > 0.f ? t1 : 0.f;
    a[4 * i + 2] = t2 > 0.f ? t2 : 0.f;
    a[4 * i + 3] = t3 > 0.f ? t3 : 0.f;
  }
  float o[NF2];
#pragma unroll
  for (int g = 0; g < NF2; ++g) {
    float acc = 0.f;
#pragma unroll
    for (int f = 0; f < NF1; ++f) acc = fmaf(a[f], W2s[f * NF2 + g], acc);
    o[g] = acc * dv;
  }
  float4* orow = (float4*)(h2s + (size_t)v * NF2);
#pragma unroll
  for (int i = 0; i < NF2 / 4; ++i)
    orow[i] = make_float4(o[4 * i], o[4 * i + 1], o[4 * i + 2], o[4 * i + 3]);
}

// ---------------- layer-2 scatter: out[d] += h2s[s], 40 lanes per edge ----------------
__global__ void k_scatter2(const int* __restrict__ src, const int* __restrict__ dst,
                           const float* __restrict__ h2s, float* __restrict__ out, int E) {
  int t = blockIdx.x * 320 + threadIdx.x;  // 320 = 8 edges * 40
  int e = t / NF2, g = t % NF2;
  if (e < E) {
    int s = src[e], d = dst[e];
    atomicAdd(&out[(size_t)d * NF2 + g], h2s[(size_t)s * NF2 + g]);
  }
}

// ---------------- finalize2 + log_softmax, one thread per node, in-place on out ----------------
__global__ void k_fin2(float* __restrict__ out, const float* __restrict__ h2s,
                       const float* __restrict__ dinv, const float* __restrict__ b2, int n) {
  __shared__ float b2s[NF2];
  if (threadIdx.x < NF2) b2s[threadIdx.x] = b2[threadIdx.x];
  __syncthreads();
  int v = blockIdx.x * 256 + threadIdx.x;
  if (v >= n) return;
  float dv = dinv[v];
  const float4* ar = (const float4*)(out + (size_t)v * NF2);
  const float4* hr = (const float4*)(h2s + (size_t)v * NF2);
  float z[NF2];
  float m = -1e30f;
#pragma unroll
  for (int i = 0; i < NF2 / 4; ++i) {
    float4 av = ar[i], hv = hr[i];
    z[4 * i + 0] = dv * (av.x + hv.x) + b2s[4 * i + 0];
    z[4 * i + 1] = dv * (av.y + hv.y) + b2s[4 * i + 1];
    z[4 * i + 2] = dv * (av.z + hv.z) + b2s[4 * i + 2];
    z[4 * i + 3] = dv * (av.w + hv.w) + b2s[4 * i + 3];
    m = fmaxf(m, fmaxf(fmaxf(z[4 * i], z[4 * i + 1]), fmaxf(z[4 * i + 2], z[4 * i + 3])));
  }
  float sum = 0.f;
#pragma unroll
  for (int g = 0; g < NF2; ++g) sum += __expf(z[g] - m);
  float ls = m + __logf(sum);
  float4* orow = (float4*)(out + (size_t)v * NF2);
#pragma unroll
  for (int i = 0; i < NF2 / 4; ++i)
    orow[i] = make_float4(z[4 * i] - ls, z[4 * i + 1] - ls, z[4 * i + 2] - ls, z[4 * i + 3] - ls);
}

extern "C" void kernel_launch(void* const* d_in, const int* in_sizes, int n_in,
                              void* d_out, int out_size, void* d_ws, size_t ws_size,
                              hipStream_t stream) {
  const float* x  = (const float*)d_in[0];
  const int*   ei = (const int*)d_in[1];
  const float* W1 = (const float*)d_in[2];
  const float* b1 = (const float*)d_in[3];
  const float* W2 = (const float*)d_in[4];
  const float* b2 = (const float*)d_in[5];
  int n = in_sizes[0] / NFEAT_IN;  // 100000
  int E = in_sizes[1] / 2;         // 3200000
  const int* src = ei;
  const int* dst = ei + E;
  float* out = (float*)d_out;

  // workspace layout (bytes): [deg: n*4][agg1: n*16*4][dinv: n*4][h1s: n*16*4][h2s: n*40*4]
  char* ws = (char*)d_ws;
  int*   deg  = (int*)ws;
  float* agg1 = (float*)(ws + (size_t)n * 4);
  float* dinv = (float*)(ws + (size_t)n * 4 * 17);
  float* h1s  = dinv + n;
  float* h2s  = h1s + (size_t)n * NF1;

  // zero deg+agg1 (contiguous) and the output accumulator
  hipMemsetAsync(d_ws, 0, (size_t)n * 17 * 4, stream);
  hipMemsetAsync(d_out, 0, (size_t)out_size * 4, stream);

  k_count<<<(E + 255) / 256, 256, 0, stream>>>(dst, deg, E);
  k_dinv<<<(n + 255) / 256, 256, 0, stream>>>(deg, dinv, n);
  k_gemm1<<<(n * NF1 + 255) / 256, 256, 0, stream>>>(x, W1, dinv, h1s, n);
  k_scatter1<<<((size_t)E * NF1 + 255) / 256, 256, 0, stream>>>(src, dst, h1s, agg1, E);
  k_fin1g2<<<(n + 255) / 256, 256, 0, stream>>>(agg1, h1s, dinv, b1, W2, h2s, n);
  k_scatter2<<<((size_t)E * NF2 + 319) / 320, 320, 0, stream>>>(src, dst, h2s, out, E);
  k_fin2<<<(n + 255) / 256, 256, 0, stream>>>(out, h2s, dinv, b2, n);
}

// Round 3
// 881.824 us; speedup vs baseline: 1.4277x; 1.4277x over previous
//
#include <hip/hip_runtime.h>

// 2-layer GCN, N=100000, E=3200000, feats 512 -> 16 -> 40.
//
// out[d] = dinv[d]*(sum_{s->d} h[s]*dinv[s] + h[d]*dinv[d]) + b,  dinv = rsqrt(deg+1)
//
// Round-3 structure:
//  * W2 postponed past aggregation (linearity) -> both aggregations are 16-feat.
//  * On-device CSR (deg -> prefix-scan -> cursor fill) -> gather-only aggregation,
//    no fp32 atomics (round-2 profile: 128M mem-side atomics = 500MB writes, 543us).

#define NFEAT_IN 512
#define NF1 16
#define NF2 40

// ---------------- degree histogram ----------------
__global__ void k_count(const int* __restrict__ dst, int* __restrict__ deg, int E) {
  int e = blockIdx.x * 256 + threadIdx.x;
  if (e < E) atomicAdd(&deg[dst[e]], 1);
}

__global__ void k_dinv(const int* __restrict__ deg, float* __restrict__ dinv, int n) {
  int v = blockIdx.x * 256 + threadIdx.x;
  if (v < n) dinv[v] = rsqrtf((float)(deg[v] + 1));  // +1 self-loop
}

// ---------------- prefix scan (3-kernel hierarchical) ----------------
__global__ void k_scan1(const int* __restrict__ deg, int* __restrict__ scanb,
                        int* __restrict__ bsum, int n) {
  __shared__ int s[256];
  int i = blockIdx.x * 256 + threadIdx.x;
  s[threadIdx.x] = (i < n) ? deg[i] : 0;
  __syncthreads();
#pragma unroll
  for (int off = 1; off < 256; off <<= 1) {
    int t = (threadIdx.x >= off) ? s[threadIdx.x - off] : 0;
    __syncthreads();
    s[threadIdx.x] += t;
    __syncthreads();
  }
  if (i < n) scanb[i] = s[threadIdx.x];  // block-local inclusive
  if (threadIdx.x == 255) bsum[blockIdx.x] = s[255];
}

__global__ void k_scan2(const int* __restrict__ bsum, int* __restrict__ boff, int nb) {
  __shared__ int s[512];
  int t = threadIdx.x;
  s[t] = (t < nb) ? bsum[t] : 0;
  __syncthreads();
#pragma unroll
  for (int off = 1; off < 512; off <<= 1) {
    int v = (t >= off) ? s[t - off] : 0;
    __syncthreads();
    s[t] += v;
    __syncthreads();
  }
  if (t < nb) boff[t] = (t > 0) ? s[t - 1] : 0;  // exclusive block offsets
}

__global__ void k_scan3(const int* __restrict__ scanb, const int* __restrict__ deg,
                        const int* __restrict__ boff, int* __restrict__ rp,
                        int* __restrict__ cursor, int n, int E) {
  int i = blockIdx.x * 256 + threadIdx.x;
  if (i < n) {
    int excl = scanb[i] - deg[i] + boff[blockIdx.x];
    rp[i] = excl;
    cursor[i] = excl;
  }
  if (i == 0) rp[n] = E;
}

// ---------------- CSR fill: esrc sorted by dst ----------------
__global__ void k_fill(const int* __restrict__ src, const int* __restrict__ dst,
                       int* __restrict__ cursor, int* __restrict__ esrc, int E) {
  int e = blockIdx.x * 256 + threadIdx.x;
  if (e < E) {
    int pos = atomicAdd(&cursor[dst[e]], 1);
    esrc[pos] = src[e];
  }
}

// ---------------- layer-1 gemm: h1s[v][f] = dinv[v]*sum_k x[v][k]*W1[k][f] ----------------
__global__ void k_gemm1(const float* __restrict__ x, const float* __restrict__ W1,
                        const float* __restrict__ dinv, float* __restrict__ h1s, int n) {
  __shared__ float Wt[NF1][NFEAT_IN + 4];
  for (int i = threadIdx.x; i < NFEAT_IN * NF1; i += 256) {
    int k = i >> 4, f = i & 15;
    Wt[f][k] = W1[i];  // W1 is [512][16] row-major
  }
  __syncthreads();
  int tid = blockIdx.x * 256 + threadIdx.x;
  int v = tid >> 4, f = tid & 15;
  if (v >= n) return;
  const float4* xr = (const float4*)(x + (size_t)v * NFEAT_IN);
  const float4* wr = (const float4*)(&Wt[f][0]);
  float acc = 0.f;
#pragma unroll 8
  for (int k4 = 0; k4 < NFEAT_IN / 4; ++k4) {
    float4 a = xr[k4], w = wr[k4];
    acc = fmaf(a.x, w.x, acc);
    acc = fmaf(a.y, w.y, acc);
    acc = fmaf(a.z, w.z, acc);
    acc = fmaf(a.w, w.w, acc);
  }
  h1s[tid] = acc * dinv[v];
}

// ---------------- CSR aggregation, 16 lanes per node, gather-only ----------------
// LAYER1: out = relu(dinv*sum + b1) * dinv      (activation pre-scaled for layer-2)
// else:   out = dinv*sum                        (pre-W2, fully normalized)
template <bool LAYER1>
__global__ void k_agg(const int* __restrict__ rp, const int* __restrict__ esrc,
                      const float* __restrict__ h, const float* __restrict__ dinv,
                      const float* __restrict__ b1, float* __restrict__ outp, int n) {
  int t = blockIdx.x * 256 + threadIdx.x;
  int v = t >> 4, f = t & 15;
  if (v >= n) return;
  int beg = rp[v], end = rp[v + 1];
  float sum = h[t];  // self-loop contribution h[v][f]
  int e = beg;
  for (; e + 4 <= end; e += 4) {  // 4 gathers in flight per lane
    int s0 = esrc[e], s1 = esrc[e + 1], s2 = esrc[e + 2], s3 = esrc[e + 3];
    float a0 = h[s0 * NF1 + f], a1 = h[s1 * NF1 + f];
    float a2 = h[s2 * NF1 + f], a3 = h[s3 * NF1 + f];
    sum += (a0 + a1) + (a2 + a3);
  }
  for (; e < end; ++e) sum += h[esrc[e] * NF1 + f];
  float dv = dinv[v];
  if (LAYER1) {
    float a = fmaf(dv, sum, b1[f]);
    outp[t] = (a > 0.f ? a : 0.f) * dv;
  } else {
    outp[t] = dv * sum;
  }
}

// ---------------- epilogue: z = aggf@W2 + b2, log_softmax, one thread/node ----------------
__global__ void k_fin2(const float* __restrict__ aggf, const float* __restrict__ W2,
                       const float* __restrict__ b2, float* __restrict__ out, int n) {
  __shared__ float W2s[NF1 * NF2];
  __shared__ float b2s[NF2];
  for (int i = threadIdx.x; i < NF1 * NF2; i += 256) W2s[i] = W2[i];
  if (threadIdx.x < NF2) b2s[threadIdx.x] = b2[threadIdx.x];
  __syncthreads();
  int v = blockIdx.x * 256 + threadIdx.x;
  if (v >= n) return;
  float a[NF1];
  const float4* ar = (const float4*)(aggf + (size_t)v * NF1);
#pragma unroll
  for (int i = 0; i < NF1 / 4; ++i) {
    float4 av = ar[i];
    a[4 * i + 0] = av.x; a[4 * i + 1] = av.y; a[4 * i + 2] = av.z; a[4 * i + 3] = av.w;
  }
  float z[NF2];
  float m = -1e30f;
#pragma unroll
  for (int g = 0; g < NF2; ++g) {
    float acc = b2s[g];
#pragma unroll
    for (int f = 0; f < NF1; ++f) acc = fmaf(a[f], W2s[f * NF2 + g], acc);
    z[g] = acc;
    m = fmaxf(m, acc);
  }
  float sum = 0.f;
#pragma unroll
  for (int g = 0; g < NF2; ++g) sum += __expf(z[g] - m);
  float ls = m + __logf(sum);
  float4* orow = (float4*)(out + (size_t)v * NF2);
#pragma unroll
  for (int i = 0; i < NF2 / 4; ++i)
    orow[i] = make_float4(z[4 * i] - ls, z[4 * i + 1] - ls, z[4 * i + 2] - ls, z[4 * i + 3] - ls);
}

extern "C" void kernel_launch(void* const* d_in, const int* in_sizes, int n_in,
                              void* d_out, int out_size, void* d_ws, size_t ws_size,
                              hipStream_t stream) {
  const float* x  = (const float*)d_in[0];
  const int*   ei = (const int*)d_in[1];
  const float* W1 = (const float*)d_in[2];
  const float* b1 = (const float*)d_in[3];
  const float* W2 = (const float*)d_in[4];
  const float* b2 = (const float*)d_in[5];
  int n = in_sizes[0] / NFEAT_IN;  // 100000
  int E = in_sizes[1] / 2;         // 3200000
  const int* src = ei;
  const int* dst = ei + E;
  float* out = (float*)d_out;

  // workspace layout, each region 64B-aligned
  char* ws = (char*)d_ws;
  size_t off = 0;
  auto alloc = [&](size_t bytes) { size_t o = off; off = (off + bytes + 63) & ~63ULL; return o; };
  int*   deg    = (int*)(ws + alloc((size_t)n * 4));
  int*   scanb  = (int*)(ws + alloc((size_t)n * 4));
  int*   rp     = (int*)(ws + alloc((size_t)(n + 1) * 4));
  int*   cursor = (int*)(ws + alloc((size_t)n * 4));
  int*   bsum   = (int*)(ws + alloc(512 * 4));
  int*   boff   = (int*)(ws + alloc(512 * 4));
  int*   esrc   = (int*)(ws + alloc((size_t)E * 4));
  float* dinv   = (float*)(ws + alloc((size_t)n * 4));
  float* h1s    = (float*)(ws + alloc((size_t)n * NF1 * 4));  // reused as aggfin2
  float* as2    = (float*)(ws + alloc((size_t)n * NF1 * 4));
  float* aggf2  = h1s;  // h1s dead after k_agg<true>; alias for layer-2 result

  int nb = (n + 255) / 256;  // 391

  hipMemsetAsync(deg, 0, (size_t)n * 4, stream);  // only deg needs zeroing

  k_count<<<(E + 255) / 256, 256, 0, stream>>>(dst, deg, E);
  k_dinv <<<nb, 256, 0, stream>>>(deg, dinv, n);
  k_scan1<<<nb, 256, 0, stream>>>(deg, scanb, bsum, n);
  k_scan2<<<1, 512, 0, stream>>>(bsum, boff, nb);
  k_scan3<<<nb, 256, 0, stream>>>(scanb, deg, boff, rp, cursor, n, E);
  k_fill <<<(E + 255) / 256, 256, 0, stream>>>(src, dst, cursor, esrc, E);
  k_gemm1<<<((size_t)n * NF1 + 255) / 256, 256, 0, stream>>>(x, W1, dinv, h1s, n);
  k_agg<true> <<<((size_t)n * NF1 + 255) / 256, 256, 0, stream>>>(rp, esrc, h1s, dinv, b1, as2, n);
  k_agg<false><<<((size_t)n * NF1 + 255) / 256, 256, 0, stream>>>(rp, esrc, as2, dinv, b1, aggf2, n);
  k_fin2 <<<nb, 256, 0, stream>>>(aggf2, W2, b2, out, n);
}